// Round 11
// baseline (312.134 us; speedup 1.0000x reference)
//
#include <hip/hip_runtime.h>

// Complex MHA, B=4 S=1024 E=1024 H=16 DH=64.
// pack(fp32->fp16, K-concat complex trick) -> GEMM1 (256x128 block, 4 waves of
// 128x64, 32x32x16 MFMA, BK=64 single-buf, 3 blk/CU, scatter epilogue) ->
// flash complex attention (swapped-operand 32x32) -> GEMM2 (same template).

typedef _Float16 f16;
typedef _Float16 f16x8 __attribute__((ext_vector_type(8)));
typedef _Float16 f16x4 __attribute__((ext_vector_type(4)));
typedef float f32x4 __attribute__((ext_vector_type(4)));
typedef float f32x16 __attribute__((ext_vector_type(16)));

#define MFMA16(a, b, c) __builtin_amdgcn_mfma_f32_16x16x32_f16(a, b, c, 0, 0, 0)
#define MFMA32(a, b, c) __builtin_amdgcn_mfma_f32_32x32x16_f16(a, b, c, 0, 0, 0)

__device__ inline void load_lds16(const void* g, void* l) {
  __builtin_amdgcn_global_load_lds(
      (const __attribute__((address_space(1))) unsigned int*)g,
      (__attribute__((address_space(3))) unsigned int*)l, 16, 0, 0);
}

__device__ inline unsigned pkrtz(float a, float b) {
  auto t = __builtin_amdgcn_cvt_pkrtz(a, b);
  return __builtin_bit_cast(unsigned, t);
}

// ---------------- pack kernels (fp32 -> fp16, concat layouts) ----------------

__global__ void pack_x_kernel(const float* __restrict__ xr, const float* __restrict__ xi,
                              f16* __restrict__ XC) {
  int i = blockIdx.x * 256 + threadIdx.x;
  if (i >= (4096 * 2048 / 4)) return;
  int idx = i * 4;
  int m = idx >> 11, k = idx & 2047;
  const float* src = (k < 1024) ? (xr + (size_t)m * 1024 + k) : (xi + (size_t)m * 1024 + k - 1024);
  float4 v = *(const float4*)src;
  f16x4 o = {(f16)v.x, (f16)v.y, (f16)v.z, (f16)v.w};
  *(f16x4*)(XC + idx) = o;
}

__global__ void pack_wqkv_kernel(const float* __restrict__ wr, const float* __restrict__ wi,
                                 f16* __restrict__ W) {
  int i = blockIdx.x * 256 + threadIdx.x;
  if (i >= (6144 * 2048 / 4)) return;
  int idx = i * 4;
  int n = idx >> 11, k = idx & 2047;
  const float* base;
  float sgn = 1.f;
  if (n < 3072) {
    if (k < 1024) base = wr + (size_t)n * 1024 + k;
    else { base = wi + (size_t)n * 1024 + k - 1024; sgn = -1.f; }
  } else {
    int n2 = n - 3072;
    if (k < 1024) base = wi + (size_t)n2 * 1024 + k;
    else base = wr + (size_t)n2 * 1024 + k - 1024;
  }
  float4 v = *(const float4*)base;
  f16x4 o = {(f16)(sgn * v.x), (f16)(sgn * v.y), (f16)(sgn * v.z), (f16)(sgn * v.w)};
  *(f16x4*)(W + idx) = o;
}

__global__ void pack_wout_kernel(const float* __restrict__ wor, const float* __restrict__ woi,
                                 f16* __restrict__ W) {
  int i = blockIdx.x * 256 + threadIdx.x;
  if (i >= (2048 * 2048 / 4)) return;
  int idx = i * 4;
  int n = idx >> 11, k = idx & 2047;
  const float* base;
  float sgn = 1.f;
  if (n < 1024) {
    if (k < 1024) base = wor + (size_t)n * 1024 + k;
    else { base = woi + (size_t)n * 1024 + k - 1024; sgn = -1.f; }
  } else {
    int n2 = n - 1024;
    if (k < 1024) base = woi + (size_t)n2 * 1024 + k;
    else base = wor + (size_t)n2 * 1024 + k - 1024;
  }
  float4 v = *(const float4*)base;
  f16x4 o = {(f16)(sgn * v.x), (f16)(sgn * v.y), (f16)(sgn * v.z), (f16)(sgn * v.w)};
  *(f16x4*)(W + idx) = o;
}

struct GemmParams {
  f16 *QC, *KCr, *KCi, *VCT;
  const float *bpr, *bpi;
  float* out;
  const float *bor, *boi;
  int out_complex;
};

// ---------------- GEMM: 256x128 block, 4 waves of 128x64, BK=64 ---------------
// C[M,N] = A[M,2048] * B[N,2048]^T. 48 KiB LDS single-buffer, 3 blocks/CU.

template <int MODE>
__global__ __launch_bounds__(256, 2) void gemm_kernel(const f16* __restrict__ A,
                                                      const f16* __restrict__ B,
                                                      GemmParams p, int ntPerXcd) {
  const int K = 2048;
  __shared__ alignas(16) f16 sA[256 * 64];  // 32 KiB
  __shared__ alignas(16) f16 sB[128 * 64];  // 16 KiB
  const int tid = threadIdx.x;
  const int w = tid >> 6, l = tid & 63;
  const int lq = l & 31, hi = l >> 5;
  const int lin = blockIdx.x;
  const int xcd = lin & 7, idx = lin >> 3;
  const int mt = idx / ntPerXcd, ntl = idx % ntPerXcd;
  const int tm0 = mt * 256;
  const int tn0 = (xcd * ntPerXcd + ntl) * 128;
  const int wm = (w >> 1) * 128, wn = (w & 1) * 64;

  // staging (R5-proven hash): thread covers row srow+i*32, chunk scg
  const int srow = tid >> 3;
  const int scg = (tid & 7) ^ (srow & 7);
  const f16* gA = A + (size_t)(tm0 + srow) * K + scg * 8;
  const f16* gB = B + (size_t)(tn0 + srow) * K + scg * 8;
  const int dst0 = w * 512;  // f16, wave-uniform

  f32x16 acc[4][2] = {};

  for (int k0 = 0; k0 < K; k0 += 64) {
#pragma unroll
    for (int i = 0; i < 8; ++i)
      load_lds16(gA + (size_t)i * 32 * K + k0, &sA[i * 2048 + dst0]);
#pragma unroll
    for (int i = 0; i < 4; ++i)
      load_lds16(gB + (size_t)i * 32 * K + k0, &sB[i * 2048 + dst0]);
    __syncthreads();
#pragma unroll
    for (int ks = 0; ks < 4; ++ks) {
      f16x8 af[4], bf[2];
#pragma unroll
      for (int mi = 0; mi < 4; ++mi) {
        int row = wm + mi * 32 + lq;
        af[mi] = *(const f16x8*)&sA[row * 64 + (((ks * 2 + hi) ^ (row & 7)) * 8)];
      }
#pragma unroll
      for (int nj = 0; nj < 2; ++nj) {
        int row = wn + nj * 32 + lq;
        bf[nj] = *(const f16x8*)&sB[row * 64 + (((ks * 2 + hi) ^ (row & 7)) * 8)];
      }
#pragma unroll
      for (int mi = 0; mi < 4; ++mi)
#pragma unroll
        for (int nj = 0; nj < 2; ++nj)
          acc[mi][nj] = MFMA32(af[mi], bf[nj], acc[mi][nj]);
    }
    __syncthreads();
  }

  // ---- epilogue: MFMA32 C/D layout col=lane&31, row=(r&3)+8*(r>>2)+4*hi ----
#pragma unroll
  for (int mi = 0; mi < 4; ++mi)
#pragma unroll
    for (int nj = 0; nj < 2; ++nj) {
      int n = tn0 + wn + nj * 32 + lq;
      if constexpr (MODE == 0) {
        bool im = n >= 3072;
        int nn = im ? n - 3072 : n;
        float bias = im ? p.bpi[nn] : p.bpr[nn];
        int part = nn >> 10;
        int e = nn & 1023, h = e >> 6, dd = e & 63;
#pragma unroll
        for (int rg = 0; rg < 4; ++rg) {
          int m0 = tm0 + wm + mi * 32 + rg * 8 + hi * 4;
          int bb = m0 >> 10, s0 = m0 & 1023;
          size_t bh = (size_t)bb * 16 + h;
          if (part == 0) {
#pragma unroll
            for (int j = 0; j < 4; ++j)
              p.QC[(bh * 1024 + s0 + j) * 128 + (im ? 64 : 0) + dd] =
                  (f16)((acc[mi][nj][rg * 4 + j] + bias) * 0.125f);
          } else if (part == 1) {
#pragma unroll
            for (int j = 0; j < 4; ++j) {
              float v2 = acc[mi][nj][rg * 4 + j] + bias;
              size_t o = (bh * 1024 + s0 + j) * 128;
              if (!im) { p.KCr[o + dd] = (f16)v2; p.KCi[o + 64 + dd] = (f16)v2; }
              else     { p.KCr[o + 64 + dd] = (f16)(-v2); p.KCi[o + dd] = (f16)v2; }
            }
          } else {
            f16x4 vv;
#pragma unroll
            for (int j = 0; j < 4; ++j) vv[j] = (f16)(acc[mi][nj][rg * 4 + j] + bias);
            *(f16x4*)&p.VCT[((bh * 128 + (im ? 64 : 0) + dd)) * 1024 + s0] = vv;
          }
        }
      } else {
        float bias = (n < 1024) ? p.bor[n] : p.boi[n - 1024];
#pragma unroll
        for (int rg = 0; rg < 4; ++rg) {
          int m0 = tm0 + wm + mi * 32 + rg * 8 + hi * 4;
#pragma unroll
          for (int j = 0; j < 4; ++j) {
            float v2 = acc[mi][nj][rg * 4 + j] + bias;
            size_t m = (size_t)(m0 + j);
            if (n < 1024) {
              if (p.out_complex) p.out[(m * 1024 + n) * 2] = v2;
              else p.out[m * 1024 + n] = v2;
            } else {
              if (p.out_complex) p.out[(m * 1024 + n - 1024) * 2 + 1] = v2;
            }
          }
        }
      }
    }
}

// ---------------- flash complex attention (swapped-operand 32x32) -------------

__global__ __launch_bounds__(512, 2) void attn_kernel(const f16* __restrict__ QC,
                                                      const f16* __restrict__ KCr,
                                                      const f16* __restrict__ KCi,
                                                      const f16* __restrict__ VCT,
                                                      f16* __restrict__ OC) {
  __shared__ alignas(16) f16 sKr[2][32 * 128];
  __shared__ alignas(16) f16 sKi[2][32 * 128];
  __shared__ alignas(16) f16 sV[2][128 * 32];
  const int tid = threadIdx.x;
  const int w = tid >> 6, l = tid & 63;
  const int lq = l & 31, hi = l >> 5;
  const int bid = blockIdx.x;
  const int xx = bid & 7, yy = bid >> 3;
  const int bh = xx + ((yy >> 2) << 3);
  const int qt = yy & 3;
  const int q0 = qt * 256 + w * 32;
  const f16* Qb = QC + (size_t)bh * 1024 * 128;
  const f16* Krb = KCr + (size_t)bh * 1024 * 128;
  const f16* Kib = KCi + (size_t)bh * 1024 * 128;
  const f16* Vb = VCT + (size_t)bh * 128 * 1024;

  f16x8 qf[8];
#pragma unroll
  for (int c = 0; c < 8; ++c)
    qf[c] = *(const f16x8*)&Qb[(size_t)(q0 + lq) * 128 + c * 16 + hi * 8];

  f32x16 accR[4] = {};
  f32x16 accI[4] = {};
  float m_r = -1e30f, l_r = 0.f, m_i = -1e30f, l_i = 0.f;

  const int sprow = tid >> 3;
  const int cK = (tid & 7) ^ ((tid >> 4) & 7);
  const f16* gKr = Krb + (size_t)(tid >> 4) * 128 + ((tid >> 3) & 1) * 64 + cK * 8;
  const f16* gKi = Kib + (size_t)(tid >> 4) * 128 + ((tid >> 3) & 1) * 64 + cK * 8;
  const int cV = (tid & 7) ^ (sprow & 7);
  const f16* gV = Vb + (size_t)(sprow * 2 + (cV >> 2)) * 1024 + (cV & 3) * 8;
  const int ldsW = w * 512;

#define STAGE(s, k0)                                                 \
  do {                                                               \
    load_lds16(gKr + (size_t)(k0) * 128, &sKr[s][ldsW]);             \
    load_lds16(gKi + (size_t)(k0) * 128, &sKi[s][ldsW]);             \
    load_lds16(gV + (k0), &sV[s][ldsW]);                             \
  } while (0)

  STAGE(0, 0);
  asm volatile("s_waitcnt vmcnt(0)" ::: "memory");
  __syncthreads();
  int cur = 0;

  for (int t = 0; t < 32; ++t) {
    if (t < 31) STAGE(cur ^ 1, (t + 1) * 32);

    f32x16 sr = {}, si = {};
    __builtin_amdgcn_s_setprio(1);
#pragma unroll
    for (int c = 0; c < 8; ++c) {
      int fc = c * 2 + hi;
      int prow = lq * 2 + (fc >> 3);
      int swzc = (fc & 7) ^ (lq & 7);
      f16x8 kr = *(const f16x8*)&sKr[cur][prow * 64 + swzc * 8];
      f16x8 ki = *(const f16x8*)&sKi[cur][prow * 64 + swzc * 8];
      sr = MFMA32(kr, qf[c], sr);
      si = MFMA32(ki, qf[c], si);
    }
    __builtin_amdgcn_s_setprio(0);

    f16x8 prf[2], pif[2];
#pragma unroll
    for (int part = 0; part < 2; ++part) {
      const f32x16& s = part ? si : sr;
      float& m = part ? m_i : m_r;
      float& lsum = part ? l_i : l_r;
      f32x16* acc = part ? accI : accR;
      float vm = s[0];
#pragma unroll
      for (int j = 1; j < 16; ++j) vm = fmaxf(vm, s[j]);
      vm = fmaxf(vm, __shfl_xor(vm, 32));
      if (__any(vm > m + 8.f)) {
        float mn = fmaxf(m, vm);
        float sc = __expf(m - mn);
        lsum *= sc;
#pragma unroll
        for (int a = 0; a < 4; ++a)
#pragma unroll
          for (int j = 0; j < 16; ++j) acc[a][j] *= sc;
        m = mn;
      }
      float p[16];
      float ls = 0.f;
#pragma unroll
      for (int j = 0; j < 16; ++j) { p[j] = __expf(s[j] - m); ls += p[j]; }
      lsum += ls;
      unsigned a0 = pkrtz(p[0], p[1]), b0 = pkrtz(p[4], p[5]);
      unsigned a1 = pkrtz(p[2], p[3]), b1 = pkrtz(p[6], p[7]);
      unsigned a2 = pkrtz(p[8], p[9]), b2 = pkrtz(p[12], p[13]);
      unsigned a3 = pkrtz(p[10], p[11]), b3 = pkrtz(p[14], p[15]);
      asm("v_permlane32_swap_b32 %0, %1" : "+v"(a0), "+v"(b0));
      asm("v_permlane32_swap_b32 %0, %1" : "+v"(a1), "+v"(b1));
      asm("v_permlane32_swap_b32 %0, %1" : "+v"(a2), "+v"(b2));
      asm("v_permlane32_swap_b32 %0, %1" : "+v"(a3), "+v"(b3));
      union { unsigned u[4]; f16x8 v; } f0, f1;
      f0.u[0] = a0; f0.u[1] = a1; f0.u[2] = b0; f0.u[3] = b1;
      f1.u[0] = a2; f1.u[1] = a3; f1.u[2] = b2; f1.u[3] = b3;
      if (part) { pif[0] = f0.v; pif[1] = f1.v; }
      else      { prf[0] = f0.v; prf[1] = f1.v; }
    }

    __builtin_amdgcn_s_setprio(1);
#pragma unroll
    for (int ft = 0; ft < 4; ++ft) {
#pragma unroll
      for (int ks = 0; ks < 2; ++ks) {
        int feat = ft * 32 + lq;
        int prow = feat >> 1;
        int swzc = (((feat & 1) * 4 + ks * 2 + hi) ^ (prow & 7));
        f16x8 vf = *(const f16x8*)&sV[cur][prow * 64 + swzc * 8];
        accR[ft] = MFMA32(vf, prf[ks], accR[ft]);
        accI[ft] = MFMA32(vf, pif[ks], accI[ft]);
      }
    }
    __builtin_amdgcn_s_setprio(0);

    asm volatile("s_waitcnt vmcnt(0)" ::: "memory");
    __syncthreads();
    cur ^= 1;
  }
#undef STAGE

  float lr = l_r + __shfl_xor(l_r, 32);
  float li = l_i + __shfl_xor(l_i, 32);
  float ilr = 1.f / lr, ili = 1.f / li;
  const int bb = bh >> 4, h = bh & 15;
  const int q = q0 + lq;
  f16* rowp = OC + ((size_t)bb * 1024 + q) * 2048 + h * 64;
#pragma unroll
  for (int tt = 0; tt < 2; ++tt) {
#pragma unroll
    for (int g = 0; g < 4; ++g) {
      int d0 = tt * 32 + g * 8 + hi * 4;
      f16x4 ov, oiv;
#pragma unroll
      for (int j = 0; j < 4; ++j) {
        int rg = g * 4 + j;
        float orv = accR[tt][rg] * ilr - accI[tt + 2][rg] * ili;
        float oivv = accR[tt + 2][rg] * ilr + accI[tt][rg] * ili;
        ov[j] = (f16)orv;
        oiv[j] = (f16)oivv;
      }
      *(f16x4*)(rowp + d0) = ov;
      *(f16x4*)(rowp + 1024 + d0) = oiv;
    }
  }
}

// ---------------- launcher ----------------------------------------------------

extern "C" void kernel_launch(void* const* d_in, const int* in_sizes, int n_in,
                              void* d_out, int out_size, void* d_ws, size_t ws_size,
                              hipStream_t stream) {
  const float* xr = (const float*)d_in[0];
  const float* xi = (const float*)d_in[1];
  const float* wpr = (const float*)d_in[2];
  const float* wpi = (const float*)d_in[3];
  const float* bpr = (const float*)d_in[4];
  const float* bpi = (const float*)d_in[5];
  const float* wor = (const float*)d_in[6];
  const float* woi = (const float*)d_in[7];
  const float* bor = (const float*)d_in[8];
  const float* boi = (const float*)d_in[9];

  f16* ws = (f16*)d_ws;
  f16* XC = ws;                       // 4096*2048
  f16* WQKV = XC + 8388608;           // 6144*2048
  f16* QC = WQKV + 12582912;          // 64*1024*128
  f16* KCr = QC + 8388608;
  f16* KCi = KCr + 8388608;
  f16* VCT = KCi + 8388608;           // 64*128*1024
  f16* OC = VCT + 8388608;            // 4096*2048
  f16* WOUT = OC + 8388608;           // 2048*2048

  pack_x_kernel<<<8192, 256, 0, stream>>>(xr, xi, XC);
  pack_wqkv_kernel<<<12288, 256, 0, stream>>>(wpr, wpi, WQKV);
  pack_wout_kernel<<<4096, 256, 0, stream>>>(wor, woi, WOUT);

  GemmParams p1 = {};
  p1.QC = QC; p1.KCr = KCr; p1.KCi = KCi; p1.VCT = VCT;
  p1.bpr = bpr; p1.bpi = bpi;
  // M: 16 tiles of 256; N: 48 tiles of 128 = 8 XCD x 6
  gemm_kernel<0><<<768, 256, 0, stream>>>(XC, WQKV, p1, 6);

  attn_kernel<<<256, 512, 0, stream>>>(QC, KCr, KCi, VCT, OC);

  GemmParams p2 = {};
  p2.out = (float*)d_out; p2.bor = bor; p2.boi = boi;
  p2.out_complex = (out_size == 8388608) ? 1 : 0;
  int ntPer = p2.out_complex ? 2 : 1;  // N = 2048 or 1024
  gemm_kernel<1><<<8 * 16 * ntPer, 256, 0, stream>>>(OC, WOUT, p2, ntPer);
}

// Round 14
// 306.430 us; speedup vs baseline: 1.0186x; 1.0186x over previous
//
#include <hip/hip_runtime.h>

// Complex MHA, B=4 S=1024 E=1024 H=16 DH=64.
// pack(fp32->fp16, K-concat complex trick) -> GEMM1 (256x128 BK=32, counted-
// vmcnt ledger pipeline, 2 blk/CU, scatter epilogue) -> flash complex attention
// (swapped-operand 32x32) -> GEMM2 (m97 128^2).

typedef _Float16 f16;
typedef _Float16 f16x8 __attribute__((ext_vector_type(8)));
typedef _Float16 f16x4 __attribute__((ext_vector_type(4)));
typedef float f32x4 __attribute__((ext_vector_type(4)));
typedef float f32x16 __attribute__((ext_vector_type(16)));

#define MFMA16(a, b, c) __builtin_amdgcn_mfma_f32_16x16x32_f16(a, b, c, 0, 0, 0)
#define MFMA32(a, b, c) __builtin_amdgcn_mfma_f32_32x32x16_f16(a, b, c, 0, 0, 0)

__device__ inline void load_lds16(const void* g, void* l) {
  __builtin_amdgcn_global_load_lds(
      (const __attribute__((address_space(1))) unsigned int*)g,
      (__attribute__((address_space(3))) unsigned int*)l, 16, 0, 0);
}

__device__ inline unsigned pkrtz(float a, float b) {
  auto t = __builtin_amdgcn_cvt_pkrtz(a, b);
  return __builtin_bit_cast(unsigned, t);
}

// ---------------- pack kernels (fp32 -> fp16, concat layouts) ----------------

__global__ void pack_x_kernel(const float* __restrict__ xr, const float* __restrict__ xi,
                              f16* __restrict__ XC) {
  int i = blockIdx.x * 256 + threadIdx.x;
  if (i >= (4096 * 2048 / 4)) return;
  int idx = i * 4;
  int m = idx >> 11, k = idx & 2047;
  const float* src = (k < 1024) ? (xr + (size_t)m * 1024 + k) : (xi + (size_t)m * 1024 + k - 1024);
  float4 v = *(const float4*)src;
  f16x4 o = {(f16)v.x, (f16)v.y, (f16)v.z, (f16)v.w};
  *(f16x4*)(XC + idx) = o;
}

__global__ void pack_wqkv_kernel(const float* __restrict__ wr, const float* __restrict__ wi,
                                 f16* __restrict__ W) {
  int i = blockIdx.x * 256 + threadIdx.x;
  if (i >= (6144 * 2048 / 4)) return;
  int idx = i * 4;
  int n = idx >> 11, k = idx & 2047;
  const float* base;
  float sgn = 1.f;
  if (n < 3072) {
    if (k < 1024) base = wr + (size_t)n * 1024 + k;
    else { base = wi + (size_t)n * 1024 + k - 1024; sgn = -1.f; }
  } else {
    int n2 = n - 3072;
    if (k < 1024) base = wi + (size_t)n2 * 1024 + k;
    else base = wr + (size_t)n2 * 1024 + k - 1024;
  }
  float4 v = *(const float4*)base;
  f16x4 o = {(f16)(sgn * v.x), (f16)(sgn * v.y), (f16)(sgn * v.z), (f16)(sgn * v.w)};
  *(f16x4*)(W + idx) = o;
}

__global__ void pack_wout_kernel(const float* __restrict__ wor, const float* __restrict__ woi,
                                 f16* __restrict__ W) {
  int i = blockIdx.x * 256 + threadIdx.x;
  if (i >= (2048 * 2048 / 4)) return;
  int idx = i * 4;
  int n = idx >> 11, k = idx & 2047;
  const float* base;
  float sgn = 1.f;
  if (n < 1024) {
    if (k < 1024) base = wor + (size_t)n * 1024 + k;
    else { base = woi + (size_t)n * 1024 + k - 1024; sgn = -1.f; }
  } else {
    int n2 = n - 1024;
    if (k < 1024) base = woi + (size_t)n2 * 1024 + k;
    else base = wor + (size_t)n2 * 1024 + k - 1024;
  }
  float4 v = *(const float4*)base;
  f16x4 o = {(f16)(sgn * v.x), (f16)(sgn * v.y), (f16)(sgn * v.z), (f16)(sgn * v.w)};
  *(f16x4*)(W + idx) = o;
}

struct GemmParams {
  f16 *QC, *KCr, *KCi, *VCT;
  const float *bpr, *bpi;
  float* out;
  const float *bor, *boi;
  int out_complex;
};

// ---------------- GEMM1: 256x128 BK=32, counted-vmcnt ledger pipeline ---------
// C[4096,6144] = A * B^T. 4 waves (2Mx2N), wave tile 128x64 (8x4 MFMA16 frags).
// LDS 48 KiB (2-buf A:16K + B:8K). Stage units: A-tile = 4 gloads, B = 2.
// Ledger (verified): end of tile t leaves STGA(t+2)x4 outstanding; every unit
// fully drains >=1 vmcnt+barrier before its reader. Tail (t>=62): drain to 0.
// NOTE: macro k0 arg is a raw f16 offset (R12/R13 bug: macro also multiplied
// by 32, staging k=(t+1)*1024 garbage).

__global__ __launch_bounds__(256, 2) void gemm1_kernel(const f16* __restrict__ A,
                                                       const f16* __restrict__ B,
                                                       GemmParams p) {
  const int K = 2048;
  __shared__ alignas(16) f16 sA[2][8192];  // [buf][256 rows x 32 f16 (64B rows)]
  __shared__ alignas(16) f16 sB[2][4096];  // [buf][128 rows x 32 f16]
  const int tid = threadIdx.x;
  const int w = tid >> 6, l = tid & 63;
  const int lr = l & 15, lk = l >> 4;
  const int lin = blockIdx.x;
  const int xcd = lin & 7, idx = lin >> 3;
  const int mt = idx / 6, ntl = idx % 6;
  const int tm0 = mt * 256;
  const int tn0 = (xcd * 6 + ntl) * 128;
  const int wm = (w >> 1) * 128, wn = (w & 1) * 64;

  // staging: 16B unit s=tid covers row s>>2 of the call, pos s&3; logical chunk
  // at pos p of row r is p ^ ((r>>1)&3) -> source k-chunk pre-applies it.
  const int srow = tid >> 2;
  const int sk8 = ((tid & 3) ^ ((tid >> 3) & 3)) * 8;
  const f16* gA = A + (size_t)(tm0 + srow) * K + sk8;
  const f16* gB = B + (size_t)(tn0 + srow) * K + sk8;
  const int dst = w * 512;  // f16, wave piece of each 4KB call

#define STGA(buf, k0) do {                                                    \
    load_lds16(gA + (size_t)(k0), &sA[buf][dst]);                             \
    load_lds16(gA + (size_t)64 * K + (size_t)(k0), &sA[buf][2048 + dst]);     \
    load_lds16(gA + (size_t)128 * K + (size_t)(k0), &sA[buf][4096 + dst]);    \
    load_lds16(gA + (size_t)192 * K + (size_t)(k0), &sA[buf][6144 + dst]);    \
  } while (0)
#define STGB(buf, k0) do {                                                    \
    load_lds16(gB + (size_t)(k0), &sB[buf][dst]);                             \
    load_lds16(gB + (size_t)64 * K + (size_t)(k0), &sB[buf][2048 + dst]);     \
  } while (0)

  f32x4 acc[8][4] = {};

  // prologue: A(0), B(0), A(1); full drain once.
  STGA(0, 0);
  STGB(0, 0);
  STGA(1, 32);
  asm volatile("s_waitcnt vmcnt(0)" ::: "memory");
  __builtin_amdgcn_s_barrier();

  const int ca = (lk ^ ((lr >> 1) & 3)) * 8;  // uniform chunk pos (rows %16 aligned)

  for (int t = 0; t < 64; ++t) {
    const int buf = t & 1;
    const f16* pA = &sA[buf][0];
    const f16* pB = &sB[buf][0];
    f16x8 af[8], bf[4];

    // ---- phase 1: read af0-7 + bf0-1 | stage B(t+1) | 16 MFMA (nj0-1) ----
#pragma unroll
    for (int mi = 0; mi < 8; ++mi)
      af[mi] = *(const f16x8*)&pA[(wm + mi * 16 + lr) * 32 + ca];
#pragma unroll
    for (int nj = 0; nj < 2; ++nj)
      bf[nj] = *(const f16x8*)&pB[(wn + nj * 16 + lr) * 32 + ca];
    if (t < 63) STGB(buf ^ 1, (t + 1) * 32);
    __builtin_amdgcn_s_barrier();
    asm volatile("s_waitcnt lgkmcnt(0)" ::: "memory");
    __builtin_amdgcn_sched_barrier(0);
    __builtin_amdgcn_s_setprio(1);
#pragma unroll
    for (int mi = 0; mi < 8; ++mi)
#pragma unroll
      for (int nj = 0; nj < 2; ++nj)
        acc[mi][nj] = MFMA16(af[mi], bf[nj], acc[mi][nj]);
    __builtin_amdgcn_s_setprio(0);
    asm volatile("s_waitcnt vmcnt(4)" ::: "memory");
    __builtin_amdgcn_s_barrier();

    // ---- phase 2: read bf2-3 | stage A(t+2) | 16 MFMA (nj2-3) ----
#pragma unroll
    for (int nj = 2; nj < 4; ++nj)
      bf[nj] = *(const f16x8*)&pB[(wn + nj * 16 + lr) * 32 + ca];
    if (t < 62) STGA(buf, (t + 2) * 32);
    __builtin_amdgcn_s_barrier();
    asm volatile("s_waitcnt lgkmcnt(0)" ::: "memory");
    __builtin_amdgcn_sched_barrier(0);
    __builtin_amdgcn_s_setprio(1);
#pragma unroll
    for (int mi = 0; mi < 8; ++mi)
#pragma unroll
      for (int nj = 2; nj < 4; ++nj)
        acc[mi][nj] = MFMA16(af[mi], bf[nj], acc[mi][nj]);
    __builtin_amdgcn_s_setprio(0);
    // Tail: at t>=62 ph2 stages nothing -> vmcnt(4) would be a no-op while
    // A(63)/B(63) units are still in flight. Drain fully.
    if (t < 62) asm volatile("s_waitcnt vmcnt(4)" ::: "memory");
    else asm volatile("s_waitcnt vmcnt(0)" ::: "memory");
    __builtin_amdgcn_s_barrier();
  }
#undef STGA
#undef STGB

  // ---- scatter epilogue (16x16 C/D: col=lane&15, row=lk*4+r) ----
#pragma unroll
  for (int mi = 0; mi < 8; ++mi)
#pragma unroll
    for (int nj = 0; nj < 4; ++nj) {
      int n = tn0 + wn + nj * 16 + lr;
      bool im = n >= 3072;
      int nn = im ? n - 3072 : n;
      float bias = im ? p.bpi[nn] : p.bpr[nn];
      int part = nn >> 10;
      int e = nn & 1023, h = e >> 6, dd = e & 63;
      int m0 = tm0 + wm + mi * 16 + lk * 4;
      int bb = m0 >> 10, s0 = m0 & 1023;
      size_t bh = (size_t)bb * 16 + h;
      if (part == 0) {
#pragma unroll
        for (int r = 0; r < 4; ++r)
          p.QC[(bh * 1024 + s0 + r) * 128 + (im ? 64 : 0) + dd] =
              (f16)((acc[mi][nj][r] + bias) * 0.125f);
      } else if (part == 1) {
#pragma unroll
        for (int r = 0; r < 4; ++r) {
          float v2 = acc[mi][nj][r] + bias;
          size_t o = (bh * 1024 + s0 + r) * 128;
          if (!im) { p.KCr[o + dd] = (f16)v2; p.KCi[o + 64 + dd] = (f16)v2; }
          else     { p.KCr[o + 64 + dd] = (f16)(-v2); p.KCi[o + dd] = (f16)v2; }
        }
      } else {
        f16x4 vv;
#pragma unroll
        for (int r = 0; r < 4; ++r) vv[r] = (f16)(acc[mi][nj][r] + bias);
        *(f16x4*)&p.VCT[((bh * 128 + (im ? 64 : 0) + dd)) * 1024 + s0] = vv;
      }
    }
}

// ---------------- GEMM2 (out proj): m97 128^2, proven 0-conflict --------------

__global__ __launch_bounds__(256) void gemm_out_kernel(const f16* __restrict__ A,
                                                       const f16* __restrict__ B,
                                                       GemmParams p) {
  const int K = 2048;
  __shared__ alignas(16) f16 sA[128 * 64];
  __shared__ alignas(16) f16 sB[128 * 64];
  const int tid = threadIdx.x;
  const int w = tid >> 6, l = tid & 63;
  const int lr = l & 15, lk = l >> 4;
  const int nwg = gridDim.x * gridDim.y;
  const int lin = blockIdx.y * gridDim.x + blockIdx.x;
  const int qq = nwg >> 3, rr = nwg & 7;
  const int xcd = lin & 7, off = lin >> 3;
  const int swz = (xcd < rr ? xcd * (qq + 1) : rr * (qq + 1) + (xcd - rr) * qq) + off;
  const int tm0 = (swz / gridDim.x) * 128;
  const int tn0 = (swz % gridDim.x) * 128;
  const int wm = (w >> 1) * 64, wn = (w & 1) * 64;

  f32x4 acc[4][4] = {};

  for (int k0 = 0; k0 < K; k0 += 64) {
#pragma unroll
    for (int i = 0; i < 4; ++i) {
      int slot = i * 256 + tid;
      int row = slot >> 3;
      int cg = (slot & 7) ^ (row & 7);
      load_lds16(A + (size_t)(tm0 + row) * K + k0 + cg * 8, &sA[(size_t)(i * 256 + (w << 6)) * 8]);
      load_lds16(B + (size_t)(tn0 + row) * K + k0 + cg * 8, &sB[(size_t)(i * 256 + (w << 6)) * 8]);
    }
    __syncthreads();
#pragma unroll
    for (int kk = 0; kk < 2; ++kk) {
      f16x8 af[4], bf[4];
#pragma unroll
      for (int t = 0; t < 4; ++t) {
        int rowA = wm + t * 16 + lr;
        af[t] = *(const f16x8*)&sA[rowA * 64 + ((kk * 4 + lk) ^ (rowA & 7)) * 8];
        int rowB = wn + t * 16 + lr;
        bf[t] = *(const f16x8*)&sB[rowB * 64 + ((kk * 4 + lk) ^ (rowB & 7)) * 8];
      }
#pragma unroll
      for (int mt = 0; mt < 4; ++mt)
#pragma unroll
        for (int nt = 0; nt < 4; ++nt) acc[mt][nt] = MFMA16(af[mt], bf[nt], acc[mt][nt]);
    }
    __syncthreads();
  }

#pragma unroll
  for (int mt = 0; mt < 4; ++mt)
#pragma unroll
    for (int nt = 0; nt < 4; ++nt)
#pragma unroll
      for (int r = 0; r < 4; ++r) {
        int m = tm0 + wm + mt * 16 + lk * 4 + r;
        int n = tn0 + wn + nt * 16 + lr;
        float val = acc[mt][nt][r];
        if (n < 1024) {
          float v2 = val + p.bor[n];
          if (p.out_complex) p.out[((size_t)m * 1024 + n) * 2] = v2;
          else p.out[(size_t)m * 1024 + n] = v2;
        } else {
          if (p.out_complex) p.out[((size_t)m * 1024 + n - 1024) * 2 + 1] = val + p.boi[n - 1024];
        }
      }
}

// ---------------- flash complex attention (swapped-operand 32x32) -------------

__global__ __launch_bounds__(512, 2) void attn_kernel(const f16* __restrict__ QC,
                                                      const f16* __restrict__ KCr,
                                                      const f16* __restrict__ KCi,
                                                      const f16* __restrict__ VCT,
                                                      f16* __restrict__ OC) {
  __shared__ alignas(16) f16 sKr[2][32 * 128];
  __shared__ alignas(16) f16 sKi[2][32 * 128];
  __shared__ alignas(16) f16 sV[2][128 * 32];
  const int tid = threadIdx.x;
  const int w = tid >> 6, l = tid & 63;
  const int lq = l & 31, hi = l >> 5;
  const int bid = blockIdx.x;
  const int xx = bid & 7, yy = bid >> 3;
  const int bh = xx + ((yy >> 2) << 3);
  const int qt = yy & 3;
  const int q0 = qt * 256 + w * 32;
  const f16* Qb = QC + (size_t)bh * 1024 * 128;
  const f16* Krb = KCr + (size_t)bh * 1024 * 128;
  const f16* Kib = KCi + (size_t)bh * 1024 * 128;
  const f16* Vb = VCT + (size_t)bh * 128 * 1024;

  f16x8 qf[8];
#pragma unroll
  for (int c = 0; c < 8; ++c)
    qf[c] = *(const f16x8*)&Qb[(size_t)(q0 + lq) * 128 + c * 16 + hi * 8];

  f32x16 accR[4] = {};
  f32x16 accI[4] = {};
  float m_r = -1e30f, l_r = 0.f, m_i = -1e30f, l_i = 0.f;

  const int sprow = tid >> 3;
  const int cK = (tid & 7) ^ ((tid >> 4) & 7);
  const f16* gKr = Krb + (size_t)(tid >> 4) * 128 + ((tid >> 3) & 1) * 64 + cK * 8;
  const f16* gKi = Kib + (size_t)(tid >> 4) * 128 + ((tid >> 3) & 1) * 64 + cK * 8;
  const int cV = (tid & 7) ^ (sprow & 7);
  const f16* gV = Vb + (size_t)(sprow * 2 + (cV >> 2)) * 1024 + (cV & 3) * 8;
  const int ldsW = w * 512;

#define STAGE(s, k0)                                                 \
  do {                                                               \
    load_lds16(gKr + (size_t)(k0) * 128, &sKr[s][ldsW]);             \
    load_lds16(gKi + (size_t)(k0) * 128, &sKi[s][ldsW]);             \
    load_lds16(gV + (k0), &sV[s][ldsW]);                             \
  } while (0)

  STAGE(0, 0);
  asm volatile("s_waitcnt vmcnt(0)" ::: "memory");
  __syncthreads();
  int cur = 0;

  for (int t = 0; t < 32; ++t) {
    if (t < 31) STAGE(cur ^ 1, (t + 1) * 32);

    f32x16 sr = {}, si = {};
    __builtin_amdgcn_s_setprio(1);
#pragma unroll
    for (int c = 0; c < 8; ++c) {
      int fc = c * 2 + hi;
      int prow = lq * 2 + (fc >> 3);
      int swzc = (fc & 7) ^ (lq & 7);
      f16x8 kr = *(const f16x8*)&sKr[cur][prow * 64 + swzc * 8];
      f16x8 ki = *(const f16x8*)&sKi[cur][prow * 64 + swzc * 8];
      sr = MFMA32(kr, qf[c], sr);
      si = MFMA32(ki, qf[c], si);
    }
    __builtin_amdgcn_s_setprio(0);

    f16x8 prf[2], pif[2];
#pragma unroll
    for (int part = 0; part < 2; ++part) {
      const f32x16& s = part ? si : sr;
      float& m = part ? m_i : m_r;
      float& lsum = part ? l_i : l_r;
      f32x16* acc = part ? accI : accR;
      float vm = s[0];
#pragma unroll
      for (int j = 1; j < 16; ++j) vm = fmaxf(vm, s[j]);
      vm = fmaxf(vm, __shfl_xor(vm, 32));
      if (__any(vm > m + 8.f)) {
        float mn = fmaxf(m, vm);
        float sc = __expf(m - mn);
        lsum *= sc;
#pragma unroll
        for (int a = 0; a < 4; ++a)
#pragma unroll
          for (int j = 0; j < 16; ++j) acc[a][j] *= sc;
        m = mn;
      }
      float p[16];
      float ls = 0.f;
#pragma unroll
      for (int j = 0; j < 16; ++j) { p[j] = __expf(s[j] - m); ls += p[j]; }
      lsum += ls;
      unsigned a0 = pkrtz(p[0], p[1]), b0 = pkrtz(p[4], p[5]);
      unsigned a1 = pkrtz(p[2], p[3]), b1 = pkrtz(p[6], p[7]);
      unsigned a2 = pkrtz(p[8], p[9]), b2 = pkrtz(p[12], p[13]);
      unsigned a3 = pkrtz(p[10], p[11]), b3 = pkrtz(p[14], p[15]);
      asm("v_permlane32_swap_b32 %0, %1" : "+v"(a0), "+v"(b0));
      asm("v_permlane32_swap_b32 %0, %1" : "+v"(a1), "+v"(b1));
      asm("v_permlane32_swap_b32 %0, %1" : "+v"(a2), "+v"(b2));
      asm("v_permlane32_swap_b32 %0, %1" : "+v"(a3), "+v"(b3));
      union { unsigned u[4]; f16x8 v; } f0, f1;
      f0.u[0] = a0; f0.u[1] = a1; f0.u[2] = b0; f0.u[3] = b1;
      f1.u[0] = a2; f1.u[1] = a3; f1.u[2] = b2; f1.u[3] = b3;
      if (part) { pif[0] = f0.v; pif[1] = f1.v; }
      else      { prf[0] = f0.v; prf[1] = f1.v; }
    }

    __builtin_amdgcn_s_setprio(1);
#pragma unroll
    for (int ft = 0; ft < 4; ++ft) {
#pragma unroll
      for (int ks = 0; ks < 2; ++ks) {
        int feat = ft * 32 + lq;
        int prow = feat >> 1;
        int swzc = (((feat & 1) * 4 + ks * 2 + hi) ^ (prow & 7));
        f16x8 vf = *(const f16x8*)&sV[cur][prow * 64 + swzc * 8];
        accR[ft] = MFMA32(vf, prf[ks], accR[ft]);
        accI[ft] = MFMA32(vf, pif[ks], accI[ft]);
      }
    }
    __builtin_amdgcn_s_setprio(0);

    asm volatile("s_waitcnt vmcnt(0)" ::: "memory");
    __syncthreads();
    cur ^= 1;
  }
#undef STAGE

  float lr = l_r + __shfl_xor(l_r, 32);
  float li = l_i + __shfl_xor(l_i, 32);
  float ilr = 1.f / lr, ili = 1.f / li;
  const int bb = bh >> 4, h = bh & 15;
  const int q = q0 + lq;
  f16* rowp = OC + ((size_t)bb * 1024 + q) * 2048 + h * 64;
#pragma unroll
  for (int tt = 0; tt < 2; ++tt) {
#pragma unroll
    for (int g = 0; g < 4; ++g) {
      int d0 = tt * 32 + g * 8 + hi * 4;
      f16x4 ov, oiv;
#pragma unroll
      for (int j = 0; j < 4; ++j) {
        int rg = g * 4 + j;
        float orv = accR[tt][rg] * ilr - accI[tt + 2][rg] * ili;
        float oivv = accR[tt + 2][rg] * ilr + accI[tt][rg] * ili;
        ov[j] = (f16)orv;
        oiv[j] = (f16)oivv;
      }
      *(f16x4*)(rowp + d0) = ov;
      *(f16x4*)(rowp + 1024 + d0) = oiv;
    }
  }
}

// ---------------- launcher ----------------------------------------------------

extern "C" void kernel_launch(void* const* d_in, const int* in_sizes, int n_in,
                              void* d_out, int out_size, void* d_ws, size_t ws_size,
                              hipStream_t stream) {
  const float* xr = (const float*)d_in[0];
  const float* xi = (const float*)d_in[1];
  const float* wpr = (const float*)d_in[2];
  const float* wpi = (const float*)d_in[3];
  const float* bpr = (const float*)d_in[4];
  const float* bpi = (const float*)d_in[5];
  const float* wor = (const float*)d_in[6];
  const float* woi = (const float*)d_in[7];
  const float* bor = (const float*)d_in[8];
  const float* boi = (const float*)d_in[9];

  f16* ws = (f16*)d_ws;
  f16* XC = ws;                       // 4096*2048
  f16* WQKV = XC + 8388608;           // 6144*2048
  f16* QC = WQKV + 12582912;          // 64*1024*128
  f16* KCr = QC + 8388608;
  f16* KCi = KCr + 8388608;
  f16* VCT = KCi + 8388608;           // 64*128*1024
  f16* OC = VCT + 8388608;            // 4096*2048
  f16* WOUT = OC + 8388608;           // 2048*2048

  pack_x_kernel<<<8192, 256, 0, stream>>>(xr, xi, XC);
  pack_wqkv_kernel<<<12288, 256, 0, stream>>>(wpr, wpi, WQKV);
  pack_wout_kernel<<<4096, 256, 0, stream>>>(wor, woi, WOUT);

  GemmParams p1 = {};
  p1.QC = QC; p1.KCr = KCr; p1.KCi = KCi; p1.VCT = VCT;
  p1.bpr = bpr; p1.bpi = bpi;
  // 8 XCD x (16 m-tiles of 256 x 6 n-tiles of 128) = 768 blocks
  gemm1_kernel<<<768, 256, 0, stream>>>(XC, WQKV, p1);

  attn_kernel<<<256, 512, 0, stream>>>(QC, KCr, KCi, VCT, OC);

  GemmParams p2 = {};
  p2.out = (float*)d_out; p2.bor = bor; p2.boi = boi;
  p2.out_complex = (out_size == 8388608) ? 1 : 0;
  int ntilesN = p2.out_complex ? 16 : 8;
  gemm_out_kernel<<<dim3(ntilesN, 32), 256, 0, stream>>>(OC, WOUT, p2);
}

// Round 15
// 284.272 us; speedup vs baseline: 1.0980x; 1.0779x over previous
//
#include <hip/hip_runtime.h>

// Complex MHA, B=4 S=1024 E=1024 H=16 DH=64.
// pack(fp32->fp16, K-concat complex trick) -> GEMM1 (256x128 BK=32 dbuf,
// 4 waves of 128x64 MFMA16, 0-conflict 64B-row layout, prefetch-issue-first,
// 3 blk/CU, scatter epilogue) -> flash complex attention (swapped 32x32) ->
// GEMM2 (m97 128^2).

typedef _Float16 f16;
typedef _Float16 f16x8 __attribute__((ext_vector_type(8)));
typedef _Float16 f16x4 __attribute__((ext_vector_type(4)));
typedef float f32x4 __attribute__((ext_vector_type(4)));
typedef float f32x16 __attribute__((ext_vector_type(16)));

#define MFMA16(a, b, c) __builtin_amdgcn_mfma_f32_16x16x32_f16(a, b, c, 0, 0, 0)
#define MFMA32(a, b, c) __builtin_amdgcn_mfma_f32_32x32x16_f16(a, b, c, 0, 0, 0)

__device__ inline void load_lds16(const void* g, void* l) {
  __builtin_amdgcn_global_load_lds(
      (const __attribute__((address_space(1))) unsigned int*)g,
      (__attribute__((address_space(3))) unsigned int*)l, 16, 0, 0);
}

__device__ inline unsigned pkrtz(float a, float b) {
  auto t = __builtin_amdgcn_cvt_pkrtz(a, b);
  return __builtin_bit_cast(unsigned, t);
}

// ---------------- pack kernels (fp32 -> fp16, concat layouts) ----------------

__global__ void pack_x_kernel(const float* __restrict__ xr, const float* __restrict__ xi,
                              f16* __restrict__ XC) {
  int i = blockIdx.x * 256 + threadIdx.x;
  if (i >= (4096 * 2048 / 4)) return;
  int idx = i * 4;
  int m = idx >> 11, k = idx & 2047;
  const float* src = (k < 1024) ? (xr + (size_t)m * 1024 + k) : (xi + (size_t)m * 1024 + k - 1024);
  float4 v = *(const float4*)src;
  f16x4 o = {(f16)v.x, (f16)v.y, (f16)v.z, (f16)v.w};
  *(f16x4*)(XC + idx) = o;
}

__global__ void pack_wqkv_kernel(const float* __restrict__ wr, const float* __restrict__ wi,
                                 f16* __restrict__ W) {
  int i = blockIdx.x * 256 + threadIdx.x;
  if (i >= (6144 * 2048 / 4)) return;
  int idx = i * 4;
  int n = idx >> 11, k = idx & 2047;
  const float* base;
  float sgn = 1.f;
  if (n < 3072) {
    if (k < 1024) base = wr + (size_t)n * 1024 + k;
    else { base = wi + (size_t)n * 1024 + k - 1024; sgn = -1.f; }
  } else {
    int n2 = n - 3072;
    if (k < 1024) base = wi + (size_t)n2 * 1024 + k;
    else base = wr + (size_t)n2 * 1024 + k - 1024;
  }
  float4 v = *(const float4*)base;
  f16x4 o = {(f16)(sgn * v.x), (f16)(sgn * v.y), (f16)(sgn * v.z), (f16)(sgn * v.w)};
  *(f16x4*)(W + idx) = o;
}

__global__ void pack_wout_kernel(const float* __restrict__ wor, const float* __restrict__ woi,
                                 f16* __restrict__ W) {
  int i = blockIdx.x * 256 + threadIdx.x;
  if (i >= (2048 * 2048 / 4)) return;
  int idx = i * 4;
  int n = idx >> 11, k = idx & 2047;
  const float* base;
  float sgn = 1.f;
  if (n < 1024) {
    if (k < 1024) base = wor + (size_t)n * 1024 + k;
    else { base = woi + (size_t)n * 1024 + k - 1024; sgn = -1.f; }
  } else {
    int n2 = n - 1024;
    if (k < 1024) base = woi + (size_t)n2 * 1024 + k;
    else base = wor + (size_t)n2 * 1024 + k - 1024;
  }
  float4 v = *(const float4*)base;
  f16x4 o = {(f16)(sgn * v.x), (f16)(sgn * v.y), (f16)(sgn * v.z), (f16)(sgn * v.w)};
  *(f16x4*)(W + idx) = o;
}

struct GemmParams {
  f16 *QC, *KCr, *KCi, *VCT;
  const float *bpr, *bpi;
  float* out;
  const float *bor, *boi;
  int out_complex;
};

// ---------------- GEMM1: 256x128 BK=32 dbuf, simple prefetch loop -------------
// C[4096,6144] = A * B^T. 4 waves (2Mx2N), wave tile 128x64 (8x4 MFMA16).
// 64B-row layout + lk^((lr>>1)&3) read hash: measured 0 conflicts (R14).
// 12 ds_read : 32 MFMA16 per wave per K32 tile -> LDS/MFMA cycle ratio ~1.1.

__global__ __launch_bounds__(256, 3) void gemm1_kernel(const f16* __restrict__ A,
                                                       const f16* __restrict__ B,
                                                       GemmParams p) {
  const int K = 2048;
  __shared__ alignas(16) f16 sA[2][8192];  // [buf][256 rows x 32 f16 (64B rows)]
  __shared__ alignas(16) f16 sB[2][4096];  // [buf][128 rows x 32 f16]
  const int tid = threadIdx.x;
  const int w = tid >> 6, l = tid & 63;
  const int lr = l & 15, lk = l >> 4;
  const int lin = blockIdx.x;
  const int xcd = lin & 7, idx = lin >> 3;
  const int mt = idx / 6, ntl = idx % 6;
  const int tm0 = mt * 256;
  const int tn0 = (xcd * 6 + ntl) * 128;
  const int wm = (w >> 1) * 128, wn = (w & 1) * 64;

  // staging: 16B unit s=tid covers row s>>2 of the call, pos s&3; logical chunk
  // at pos pp of row r is pp ^ ((r>>1)&3) -> source k-chunk pre-applies it.
  const int srow = tid >> 2;
  const int sk8 = ((tid & 3) ^ ((tid >> 3) & 3)) * 8;
  const f16* gA = A + (size_t)(tm0 + srow) * K + sk8;
  const f16* gB = B + (size_t)(tn0 + srow) * K + sk8;
  const int dst = w * 512;  // f16, wave piece of each 4KB call

#define STGA(buf, k0) do {                                                    \
    load_lds16(gA + (size_t)(k0), &sA[buf][dst]);                             \
    load_lds16(gA + (size_t)64 * K + (size_t)(k0), &sA[buf][2048 + dst]);     \
    load_lds16(gA + (size_t)128 * K + (size_t)(k0), &sA[buf][4096 + dst]);    \
    load_lds16(gA + (size_t)192 * K + (size_t)(k0), &sA[buf][6144 + dst]);    \
  } while (0)
#define STGB(buf, k0) do {                                                    \
    load_lds16(gB + (size_t)(k0), &sB[buf][dst]);                             \
    load_lds16(gB + (size_t)64 * K + (size_t)(k0), &sB[buf][2048 + dst]);     \
  } while (0)

  f32x4 acc[8][4] = {};

  STGA(0, 0);
  STGB(0, 0);
  asm volatile("s_waitcnt vmcnt(0)" ::: "memory");
  __syncthreads();

  const int ca = (lk ^ ((lr >> 1) & 3)) * 8;  // 0-conflict chunk pos (R14-measured)

  for (int t = 0; t < 64; ++t) {
    const int buf = t & 1;
    // issue next tile's loads FIRST: latency hides under frag reads + MFMA
    if (t < 63) {
      STGA(buf ^ 1, (t + 1) * 32);
      STGB(buf ^ 1, (t + 1) * 32);
    }
    const f16* pA = &sA[buf][0];
    const f16* pB = &sB[buf][0];
    f16x8 af[8], bf[4];
#pragma unroll
    for (int mi = 0; mi < 8; ++mi)
      af[mi] = *(const f16x8*)&pA[(wm + mi * 16 + lr) * 32 + ca];
#pragma unroll
    for (int nj = 0; nj < 4; ++nj)
      bf[nj] = *(const f16x8*)&pB[(wn + nj * 16 + lr) * 32 + ca];
#pragma unroll
    for (int mi = 0; mi < 8; ++mi)
#pragma unroll
      for (int nj = 0; nj < 4; ++nj)
        acc[mi][nj] = MFMA16(af[mi], bf[nj], acc[mi][nj]);
    asm volatile("s_waitcnt vmcnt(0)" ::: "memory");
    __syncthreads();
  }
#undef STGA
#undef STGB

  // ---- scatter epilogue (16x16 C/D: col=lane&15, row=lk*4+r) ----
#pragma unroll
  for (int mi = 0; mi < 8; ++mi)
#pragma unroll
    for (int nj = 0; nj < 4; ++nj) {
      int n = tn0 + wn + nj * 16 + lr;
      bool im = n >= 3072;
      int nn = im ? n - 3072 : n;
      float bias = im ? p.bpi[nn] : p.bpr[nn];
      int part = nn >> 10;
      int e = nn & 1023, h = e >> 6, dd = e & 63;
      int m0 = tm0 + wm + mi * 16 + lk * 4;
      int bb = m0 >> 10, s0 = m0 & 1023;
      size_t bh = (size_t)bb * 16 + h;
      if (part == 0) {
#pragma unroll
        for (int r = 0; r < 4; ++r)
          p.QC[(bh * 1024 + s0 + r) * 128 + (im ? 64 : 0) + dd] =
              (f16)((acc[mi][nj][r] + bias) * 0.125f);
      } else if (part == 1) {
#pragma unroll
        for (int r = 0; r < 4; ++r) {
          float v2 = acc[mi][nj][r] + bias;
          size_t o = (bh * 1024 + s0 + r) * 128;
          if (!im) { p.KCr[o + dd] = (f16)v2; p.KCi[o + 64 + dd] = (f16)v2; }
          else     { p.KCr[o + 64 + dd] = (f16)(-v2); p.KCi[o + dd] = (f16)v2; }
        }
      } else {
        f16x4 vv;
#pragma unroll
        for (int r = 0; r < 4; ++r) vv[r] = (f16)(acc[mi][nj][r] + bias);
        *(f16x4*)&p.VCT[((bh * 128 + (im ? 64 : 0) + dd)) * 1024 + s0] = vv;
      }
    }
}

// ---------------- GEMM2 (out proj): m97 128^2, proven 0-conflict --------------

__global__ __launch_bounds__(256) void gemm_out_kernel(const f16* __restrict__ A,
                                                       const f16* __restrict__ B,
                                                       GemmParams p) {
  const int K = 2048;
  __shared__ alignas(16) f16 sA[128 * 64];
  __shared__ alignas(16) f16 sB[128 * 64];
  const int tid = threadIdx.x;
  const int w = tid >> 6, l = tid & 63;
  const int lr = l & 15, lk = l >> 4;
  const int nwg = gridDim.x * gridDim.y;
  const int lin = blockIdx.y * gridDim.x + blockIdx.x;
  const int qq = nwg >> 3, rr = nwg & 7;
  const int xcd = lin & 7, off = lin >> 3;
  const int swz = (xcd < rr ? xcd * (qq + 1) : rr * (qq + 1) + (xcd - rr) * qq) + off;
  const int tm0 = (swz / gridDim.x) * 128;
  const int tn0 = (swz % gridDim.x) * 128;
  const int wm = (w >> 1) * 64, wn = (w & 1) * 64;

  f32x4 acc[4][4] = {};

  for (int k0 = 0; k0 < K; k0 += 64) {
#pragma unroll
    for (int i = 0; i < 4; ++i) {
      int slot = i * 256 + tid;
      int row = slot >> 3;
      int cg = (slot & 7) ^ (row & 7);
      load_lds16(A + (size_t)(tm0 + row) * K + k0 + cg * 8, &sA[(size_t)(i * 256 + (w << 6)) * 8]);
      load_lds16(B + (size_t)(tn0 + row) * K + k0 + cg * 8, &sB[(size_t)(i * 256 + (w << 6)) * 8]);
    }
    __syncthreads();
#pragma unroll
    for (int kk = 0; kk < 2; ++kk) {
      f16x8 af[4], bf[4];
#pragma unroll
      for (int t = 0; t < 4; ++t) {
        int rowA = wm + t * 16 + lr;
        af[t] = *(const f16x8*)&sA[rowA * 64 + ((kk * 4 + lk) ^ (rowA & 7)) * 8];
        int rowB = wn + t * 16 + lr;
        bf[t] = *(const f16x8*)&sB[rowB * 64 + ((kk * 4 + lk) ^ (rowB & 7)) * 8];
      }
#pragma unroll
      for (int mt = 0; mt < 4; ++mt)
#pragma unroll
        for (int nt = 0; nt < 4; ++nt) acc[mt][nt] = MFMA16(af[mt], bf[nt], acc[mt][nt]);
    }
    __syncthreads();
  }

#pragma unroll
  for (int mt = 0; mt < 4; ++mt)
#pragma unroll
    for (int nt = 0; nt < 4; ++nt)
#pragma unroll
      for (int r = 0; r < 4; ++r) {
        int m = tm0 + wm + mt * 16 + lk * 4 + r;
        int n = tn0 + wn + nt * 16 + lr;
        float val = acc[mt][nt][r];
        if (n < 1024) {
          float v2 = val + p.bor[n];
          if (p.out_complex) p.out[((size_t)m * 1024 + n) * 2] = v2;
          else p.out[(size_t)m * 1024 + n] = v2;
        } else {
          if (p.out_complex) p.out[((size_t)m * 1024 + n - 1024) * 2 + 1] = val + p.boi[n - 1024];
        }
      }
}

// ---------------- flash complex attention (swapped-operand 32x32) -------------

__global__ __launch_bounds__(512, 2) void attn_kernel(const f16* __restrict__ QC,
                                                      const f16* __restrict__ KCr,
                                                      const f16* __restrict__ KCi,
                                                      const f16* __restrict__ VCT,
                                                      f16* __restrict__ OC) {
  __shared__ alignas(16) f16 sKr[2][32 * 128];
  __shared__ alignas(16) f16 sKi[2][32 * 128];
  __shared__ alignas(16) f16 sV[2][128 * 32];
  const int tid = threadIdx.x;
  const int w = tid >> 6, l = tid & 63;
  const int lq = l & 31, hi = l >> 5;
  const int bid = blockIdx.x;
  const int xx = bid & 7, yy = bid >> 3;
  const int bh = xx + ((yy >> 2) << 3);
  const int qt = yy & 3;
  const int q0 = qt * 256 + w * 32;
  const f16* Qb = QC + (size_t)bh * 1024 * 128;
  const f16* Krb = KCr + (size_t)bh * 1024 * 128;
  const f16* Kib = KCi + (size_t)bh * 1024 * 128;
  const f16* Vb = VCT + (size_t)bh * 128 * 1024;

  f16x8 qf[8];
#pragma unroll
  for (int c = 0; c < 8; ++c)
    qf[c] = *(const f16x8*)&Qb[(size_t)(q0 + lq) * 128 + c * 16 + hi * 8];

  f32x16 accR[4] = {};
  f32x16 accI[4] = {};
  float m_r = -1e30f, l_r = 0.f, m_i = -1e30f, l_i = 0.f;

  const int sprow = tid >> 3;
  const int cK = (tid & 7) ^ ((tid >> 4) & 7);
  const f16* gKr = Krb + (size_t)(tid >> 4) * 128 + ((tid >> 3) & 1) * 64 + cK * 8;
  const f16* gKi = Kib + (size_t)(tid >> 4) * 128 + ((tid >> 3) & 1) * 64 + cK * 8;
  const int cV = (tid & 7) ^ (sprow & 7);
  const f16* gV = Vb + (size_t)(sprow * 2 + (cV >> 2)) * 1024 + (cV & 3) * 8;
  const int ldsW = w * 512;

#define STAGE(s, k0)                                                 \
  do {                                                               \
    load_lds16(gKr + (size_t)(k0) * 128, &sKr[s][ldsW]);             \
    load_lds16(gKi + (size_t)(k0) * 128, &sKi[s][ldsW]);             \
    load_lds16(gV + (k0), &sV[s][ldsW]);                             \
  } while (0)

  STAGE(0, 0);
  asm volatile("s_waitcnt vmcnt(0)" ::: "memory");
  __syncthreads();
  int cur = 0;

  for (int t = 0; t < 32; ++t) {
    if (t < 31) STAGE(cur ^ 1, (t + 1) * 32);

    f32x16 sr = {}, si = {};
    __builtin_amdgcn_s_setprio(1);
#pragma unroll
    for (int c = 0; c < 8; ++c) {
      int fc = c * 2 + hi;
      int prow = lq * 2 + (fc >> 3);
      int swzc = (fc & 7) ^ (lq & 7);
      f16x8 kr = *(const f16x8*)&sKr[cur][prow * 64 + swzc * 8];
      f16x8 ki = *(const f16x8*)&sKi[cur][prow * 64 + swzc * 8];
      sr = MFMA32(kr, qf[c], sr);
      si = MFMA32(ki, qf[c], si);
    }
    __builtin_amdgcn_s_setprio(0);

    f16x8 prf[2], pif[2];
#pragma unroll
    for (int part = 0; part < 2; ++part) {
      const f32x16& s = part ? si : sr;
      float& m = part ? m_i : m_r;
      float& lsum = part ? l_i : l_r;
      f32x16* acc = part ? accI : accR;
      float vm = s[0];
#pragma unroll
      for (int j = 1; j < 16; ++j) vm = fmaxf(vm, s[j]);
      vm = fmaxf(vm, __shfl_xor(vm, 32));
      if (__any(vm > m + 8.f)) {
        float mn = fmaxf(m, vm);
        float sc = __expf(m - mn);
        lsum *= sc;
#pragma unroll
        for (int a = 0; a < 4; ++a)
#pragma unroll
          for (int j = 0; j < 16; ++j) acc[a][j] *= sc;
        m = mn;
      }
      float p[16];
      float ls = 0.f;
#pragma unroll
      for (int j = 0; j < 16; ++j) { p[j] = __expf(s[j] - m); ls += p[j]; }
      lsum += ls;
      unsigned a0 = pkrtz(p[0], p[1]), b0 = pkrtz(p[4], p[5]);
      unsigned a1 = pkrtz(p[2], p[3]), b1 = pkrtz(p[6], p[7]);
      unsigned a2 = pkrtz(p[8], p[9]), b2 = pkrtz(p[12], p[13]);
      unsigned a3 = pkrtz(p[10], p[11]), b3 = pkrtz(p[14], p[15]);
      asm("v_permlane32_swap_b32 %0, %1" : "+v"(a0), "+v"(b0));
      asm("v_permlane32_swap_b32 %0, %1" : "+v"(a1), "+v"(b1));
      asm("v_permlane32_swap_b32 %0, %1" : "+v"(a2), "+v"(b2));
      asm("v_permlane32_swap_b32 %0, %1" : "+v"(a3), "+v"(b3));
      union { unsigned u[4]; f16x8 v; } f0, f1;
      f0.u[0] = a0; f0.u[1] = a1; f0.u[2] = b0; f0.u[3] = b1;
      f1.u[0] = a2; f1.u[1] = a3; f1.u[2] = b2; f1.u[3] = b3;
      if (part) { pif[0] = f0.v; pif[1] = f1.v; }
      else      { prf[0] = f0.v; prf[1] = f1.v; }
    }

    __builtin_amdgcn_s_setprio(1);
#pragma unroll
    for (int ft = 0; ft < 4; ++ft) {
#pragma unroll
      for (int ks = 0; ks < 2; ++ks) {
        int feat = ft * 32 + lq;
        int prow = feat >> 1;
        int swzc = (((feat & 1) * 4 + ks * 2 + hi) ^ (prow & 7));
        f16x8 vf = *(const f16x8*)&sV[cur][prow * 64 + swzc * 8];
        accR[ft] = MFMA32(vf, prf[ks], accR[ft]);
        accI[ft] = MFMA32(vf, pif[ks], accI[ft]);
      }
    }
    __builtin_amdgcn_s_setprio(0);

    asm volatile("s_waitcnt vmcnt(0)" ::: "memory");
    __syncthreads();
    cur ^= 1;
  }
#undef STAGE

  float lr = l_r + __shfl_xor(l_r, 32);
  float li = l_i + __shfl_xor(l_i, 32);
  float ilr = 1.f / lr, ili = 1.f / li;
  const int bb = bh >> 4, h = bh & 15;
  const int q = q0 + lq;
  f16* rowp = OC + ((size_t)bb * 1024 + q) * 2048 + h * 64;
#pragma unroll
  for (int tt = 0; tt < 2; ++tt) {
#pragma unroll
    for (int g = 0; g < 4; ++g) {
      int d0 = tt * 32 + g * 8 + hi * 4;
      f16x4 ov, oiv;
#pragma unroll
      for (int j = 0; j < 4; ++j) {
        int rg = g * 4 + j;
        float orv = accR[tt][rg] * ilr - accI[tt + 2][rg] * ili;
        float oivv = accR[tt + 2][rg] * ilr + accI[tt][rg] * ili;
        ov[j] = (f16)orv;
        oiv[j] = (f16)oivv;
      }
      *(f16x4*)(rowp + d0) = ov;
      *(f16x4*)(rowp + 1024 + d0) = oiv;
    }
  }
}

// ---------------- launcher ----------------------------------------------------

extern "C" void kernel_launch(void* const* d_in, const int* in_sizes, int n_in,
                              void* d_out, int out_size, void* d_ws, size_t ws_size,
                              hipStream_t stream) {
  const float* xr = (const float*)d_in[0];
  const float* xi = (const float*)d_in[1];
  const float* wpr = (const float*)d_in[2];
  const float* wpi = (const float*)d_in[3];
  const float* bpr = (const float*)d_in[4];
  const float* bpi = (const float*)d_in[5];
  const float* wor = (const float*)d_in[6];
  const float* woi = (const float*)d_in[7];
  const float* bor = (const float*)d_in[8];
  const float* boi = (const float*)d_in[9];

  f16* ws = (f16*)d_ws;
  f16* XC = ws;                       // 4096*2048
  f16* WQKV = XC + 8388608;           // 6144*2048
  f16* QC = WQKV + 12582912;          // 64*1024*128
  f16* KCr = QC + 8388608;
  f16* KCi = KCr + 8388608;
  f16* VCT = KCi + 8388608;           // 64*128*1024
  f16* OC = VCT + 8388608;            // 4096*2048
  f16* WOUT = OC + 8388608;           // 2048*2048

  pack_x_kernel<<<8192, 256, 0, stream>>>(xr, xi, XC);
  pack_wqkv_kernel<<<12288, 256, 0, stream>>>(wpr, wpi, WQKV);
  pack_wout_kernel<<<4096, 256, 0, stream>>>(wor, woi, WOUT);

  GemmParams p1 = {};
  p1.QC = QC; p1.KCr = KCr; p1.KCi = KCi; p1.VCT = VCT;
  p1.bpr = bpr; p1.bpi = bpi;
  // 8 XCD x (16 m-tiles of 256 x 6 n-tiles of 128) = 768 blocks
  gemm1_kernel<<<768, 256, 0, stream>>>(XC, WQKV, p1);

  attn_kernel<<<256, 512, 0, stream>>>(QC, KCr, KCi, VCT, OC);

  GemmParams p2 = {};
  p2.out = (float*)d_out; p2.bor = bor; p2.boi = boi;
  p2.out_complex = (out_size == 8388608) ? 1 : 0;
  int ntilesN = p2.out_complex ? 16 : 8;
  gemm_out_kernel<<<dim3(ntilesN, 32), 256, 0, stream>>>(OC, WOUT, p2);
}